// Round 3
// baseline (216.720 us; speedup 1.0000x reference)
//
#include <hip/hip_runtime.h>
#include <math.h>

// B=32, F=1000, D=1024; OUT = 1+22+1+22+1+128 = 175
#define D_DIM  1024
#define OUT_N  175
#define HID_N  128
#define BM     64
#define BK     32
#define NWR    176          // padded W rows (row 175 = zeros)
#define LDK    40           // LDS row stride in bf16 elems (32 k + 8 pad = 80 B)

#define V_OFF   1
#define VG_OFF  23
#define N_OFF   24
#define NG_OFF  46
#define HF_OFF  47

#define LOG_F0_MIN 4.3820266346738812f   // ln(80)
#define LOG_F0_MAX 6.9077552789821368f   // ln(1000)
#define PI_F       3.14159265358979323846f

typedef __attribute__((ext_vector_type(8))) short s16x8;   // 8 bf16 (4 VGPR) MFMA frag
typedef __attribute__((ext_vector_type(4))) short s16x4;
typedef __attribute__((ext_vector_type(4))) float f32x4;

// fp32 -> bf16 bits, round-to-nearest-even (pure integer: no __bf16 dependency)
static __device__ __forceinline__ short f2bf(float f) {
    unsigned u = __float_as_uint(f);
    unsigned r = (u + 0x7fffu + ((u >> 16) & 1u)) >> 16;
    return (short)r;
}
static __device__ __forceinline__ float bf2f(short s) {
    return __uint_as_float(((unsigned)(unsigned short)s) << 16);
}

// ---------------- pre-kernel: split W (fp32) -> bf16 hi/lo in workspace ----------------
__global__ __launch_bounds__(256) void split_w_kernel(
    const float* __restrict__ W, short* __restrict__ whi, short* __restrict__ wlo)
{
    const int n = blockIdx.x;            // 0..175 (175 = zero pad row)
    const int k = threadIdx.x << 2;      // 0..1020
    float4 v = make_float4(0.f, 0.f, 0.f, 0.f);
    if (n < OUT_N) v = *(const float4*)(W + (size_t)n * D_DIM + k);
    s16x4 hv, lv;
    hv.x = f2bf(v.x); lv.x = f2bf(v.x - bf2f(hv.x));
    hv.y = f2bf(v.y); lv.y = f2bf(v.y - bf2f(hv.y));
    hv.z = f2bf(v.z); lv.z = f2bf(v.z - bf2f(hv.z));
    hv.w = f2bf(v.w); lv.w = f2bf(v.w - bf2f(hv.w));
    *(s16x4*)(whi + n * D_DIM + k) = hv;
    *(s16x4*)(wlo + n * D_DIM + k) = lv;
}

// ---------------- main fused kernel ----------------
// LDS (shorts): AhiS[64][40] @0, AloS @2560, WhiS[176][40] @5120, WloS @12160
//   staging total 19200 shorts = 38400 B; epilogue union yS[64][177] f32 = 45312 B
#define SMEM_BYTES 45312

__global__ __launch_bounds__(256) void glottal_main(
    const float* __restrict__ h, const short* __restrict__ whi,
    const short* __restrict__ wlo, const float* __restrict__ bias,
    float* __restrict__ out, int R)
{
    __shared__ __align__(16) char smem[SMEM_BYTES];
    short* AhiS = (short*)smem;
    short* AloS = AhiS + BM * LDK;
    short* WhiS = AloS + BM * LDK;
    short* WloS = WhiS + NWR * LDK;
    float (*yS)[OUT_N + 2] = (float (*)[OUT_N + 2])smem;   // [64][177]

    const int tid = threadIdx.x;
    const int r0  = blockIdx.x * BM;

    // staging indices
    const int rA  = tid >> 3;            // 0..31 (h rows, 2 halves)
    const int kqA = (tid & 7) << 2;      // 0,4,..,28 (fp32 float4)
    const int rW  = tid >> 2;            // 0..63 (W rows, 3 iters)
    const int kqW = (tid & 3) << 3;      // 0,8,16,24 (bf16x8)

    // MFMA indices (wave splits N: wave w owns j = 3w .. 3w+jcnt-1)
    const int lane = tid & 63;
    const int wid  = tid >> 6;
    const int c    = lane & 15;
    const int kg   = lane >> 4;
    const int jcnt = (wid < 3) ? 3 : 2;
    const int fragOff = c * LDK + kg * 8;

    f32x4 acc[4][3];
    #pragma unroll
    for (int m = 0; m < 4; ++m)
        #pragma unroll
        for (int jj = 0; jj < 3; ++jj) acc[m][jj] = f32x4{0.f, 0.f, 0.f, 0.f};

    float4 apf0, apf1;
    s16x8 wph0, wph1, wph2, wpl0, wpl1, wpl2;

    int gA0 = r0 + rA;      if (gA0 >= R) gA0 = R - 1;
    int gA1 = r0 + rA + 32; if (gA1 >= R) gA1 = R - 1;
    const float* hP0 = h + (size_t)gA0 * D_DIM + kqA;
    const float* hP1 = h + (size_t)gA1 * D_DIM + kqA;
    const int nW0 = rW, nW1 = rW + 64, nW2 = rW + 128;
    const short* wHP = whi + rW * D_DIM + kqW;
    const short* wLP = wlo + rW * D_DIM + kqW;
    const bool w2ok = (nW2 < NWR);

    // ---- prefetch tile 0 ----
    apf0 = *(const float4*)(hP0);
    apf1 = *(const float4*)(hP1);
    wph0 = *(const s16x8*)(wHP);
    wpl0 = *(const s16x8*)(wLP);
    wph1 = *(const s16x8*)(wHP + 64 * D_DIM);
    wpl1 = *(const s16x8*)(wLP + 64 * D_DIM);
    if (w2ok) { wph2 = *(const s16x8*)(wHP + 128 * D_DIM);
                wpl2 = *(const s16x8*)(wLP + 128 * D_DIM); }

    for (int kt = 0; kt < D_DIM; kt += BK) {
        // ---- split/store staged registers into LDS ----
        {
            s16x4 hv, lv;
            hv.x = f2bf(apf0.x); lv.x = f2bf(apf0.x - bf2f(hv.x));
            hv.y = f2bf(apf0.y); lv.y = f2bf(apf0.y - bf2f(hv.y));
            hv.z = f2bf(apf0.z); lv.z = f2bf(apf0.z - bf2f(hv.z));
            hv.w = f2bf(apf0.w); lv.w = f2bf(apf0.w - bf2f(hv.w));
            *(s16x4*)(AhiS + rA * LDK + kqA) = hv;
            *(s16x4*)(AloS + rA * LDK + kqA) = lv;
            hv.x = f2bf(apf1.x); lv.x = f2bf(apf1.x - bf2f(hv.x));
            hv.y = f2bf(apf1.y); lv.y = f2bf(apf1.y - bf2f(hv.y));
            hv.z = f2bf(apf1.z); lv.z = f2bf(apf1.z - bf2f(hv.z));
            hv.w = f2bf(apf1.w); lv.w = f2bf(apf1.w - bf2f(hv.w));
            *(s16x4*)(AhiS + (rA + 32) * LDK + kqA) = hv;
            *(s16x4*)(AloS + (rA + 32) * LDK + kqA) = lv;
            *(s16x8*)(WhiS + nW0 * LDK + kqW) = wph0;
            *(s16x8*)(WloS + nW0 * LDK + kqW) = wpl0;
            *(s16x8*)(WhiS + nW1 * LDK + kqW) = wph1;
            *(s16x8*)(WloS + nW1 * LDK + kqW) = wpl1;
            if (w2ok) {
                *(s16x8*)(WhiS + nW2 * LDK + kqW) = wph2;
                *(s16x8*)(WloS + nW2 * LDK + kqW) = wpl2;
            }
        }
        __syncthreads();

        // ---- prefetch next tile (hides HBM latency under MFMA) ----
        const int ktn = kt + BK;
        if (ktn < D_DIM) {
            apf0 = *(const float4*)(hP0 + ktn);
            apf1 = *(const float4*)(hP1 + ktn);
            wph0 = *(const s16x8*)(wHP + ktn);
            wpl0 = *(const s16x8*)(wLP + ktn);
            wph1 = *(const s16x8*)(wHP + 64 * D_DIM + ktn);
            wpl1 = *(const s16x8*)(wLP + 64 * D_DIM + ktn);
            if (w2ok) { wph2 = *(const s16x8*)(wHP + 128 * D_DIM + ktn);
                        wpl2 = *(const s16x8*)(wLP + 128 * D_DIM + ktn); }
        }

        // ---- fragment reads + MFMA (3-pass split-bf16) ----
        s16x8 ahv[4], alv[4];
        #pragma unroll
        for (int m = 0; m < 4; ++m) {
            ahv[m] = *(const s16x8*)(AhiS + (m << 4) * LDK + fragOff);
            alv[m] = *(const s16x8*)(AloS + (m << 4) * LDK + fragOff);
        }
        #pragma unroll
        for (int jj = 0; jj < 3; ++jj) {
            if (jj < jcnt) {                       // wave-uniform
                const int j = wid * 3 + jj;
                s16x8 bh = *(const s16x8*)(WhiS + (j << 4) * LDK + fragOff);
                s16x8 bl = *(const s16x8*)(WloS + (j << 4) * LDK + fragOff);
                #pragma unroll
                for (int m = 0; m < 4; ++m) {
                    acc[m][jj] = __builtin_amdgcn_mfma_f32_16x16x32_bf16(ahv[m], bh, acc[m][jj], 0, 0, 0);
                    acc[m][jj] = __builtin_amdgcn_mfma_f32_16x16x32_bf16(ahv[m], bl, acc[m][jj], 0, 0, 0);
                    acc[m][jj] = __builtin_amdgcn_mfma_f32_16x16x32_bf16(alv[m], bh, acc[m][jj], 0, 0, 0);
                }
            }
        }
        __syncthreads();
    }

    // ---- y tile (+bias) -> LDS.  D frag: col = 16j + c, row = 16m + 4kg + reg ----
    #pragma unroll
    for (int jj = 0; jj < 3; ++jj) {
        if (jj < jcnt) {
            const int j   = wid * 3 + jj;
            const int col = (j << 4) + c;
            if (col < OUT_N) {
                const float bb = bias[col];
                #pragma unroll
                for (int m = 0; m < 4; ++m)
                    #pragma unroll
                    for (int r = 0; r < 4; ++r)
                        yS[(m << 4) + (kg << 2) + r][col] = acc[m][jj][r] + bb;
            }
        }
    }
    __syncthreads();

    const size_t Rz = (size_t)R;

    // ---- h_feat: coalesced store (64 rows x 128 cols) ----
    for (int e = tid; e < BM * HID_N; e += 256) {
        int rr = e >> 7, cc = e & (HID_N - 1);
        int gr = r0 + rr;
        if (gr < R)
            out[Rz + (size_t)gr * HID_N + cc] = yS[rr][HF_OFF + cc];
    }

    // ---- scalars + LPC: 2 threads/row (half 0 = voice+f0, half 1 = noise) ----
    if (tid < 2 * BM) {
        const int rr   = tid >> 1;
        const int half = tid & 1;
        const int gr   = r0 + rr;
        if (gr < R) {
            const float* yrow = yS[rr];

            if (half == 0) {
                float s = 1.f / (1.f + expf(-yrow[0]));
                out[gr] = expf(s * (LOG_F0_MAX - LOG_F0_MIN) + LOG_F0_MIN);
            }

            const int lbase = half ? N_OFF  : V_OFF;
            const int gidx  = half ? NG_OFF : VG_OFF;
            float*    gout  = out + (half ? Rz * 152 : Rz * 129);
            float*    lout  = out + (half ? Rz * 153 : Rz * 130);

            gout[gr] = expf(yrow[gidx]);

            float poly[23];
            poly[0] = 1.f;
            #pragma unroll
            for (int j = 1; j < 23; ++j) poly[j] = 0.f;

            #pragma unroll
            for (int i = 0; i < 11; ++i) {
                float l0  = yrow[lbase + 2 * i];
                float l1  = yrow[lbase + 2 * i + 1];
                float mag = 0.99f / (1.f + expf(-l0));
                float ph  = PI_F   / (1.f + expf(-l1));
                float a1  = -2.f * mag * cosf(ph);
                float a2  = mag * mag;
                #pragma unroll
                for (int j = 22; j >= 2; --j)
                    poly[j] = fmaf(a1, poly[j - 1], fmaf(a2, poly[j - 2], poly[j]));
                poly[1] = fmaf(a1, poly[0], poly[1]);
            }

            #pragma unroll
            for (int j = 0; j < 22; ++j)
                lout[(size_t)gr * 22 + j] = poly[j + 1];
        }
    }
}

extern "C" void kernel_launch(void* const* d_in, const int* in_sizes, int n_in,
                              void* d_out, int out_size, void* d_ws, size_t ws_size,
                              hipStream_t stream) {
    const float* h    = (const float*)d_in[0];
    const float* W    = (const float*)d_in[1];
    const float* bias = (const float*)d_in[2];
    float* out        = (float*)d_out;

    const int R = in_sizes[0] / D_DIM;          // 32000
    const int blocks = (R + BM - 1) / BM;       // 500

    short* whi = (short*)d_ws;                  // [176][1024] bf16 hi
    short* wlo = whi + NWR * D_DIM;             // [176][1024] bf16 lo  (total 720896 B)

    split_w_kernel<<<NWR, 256, 0, stream>>>(W, whi, wlo);
    glottal_main<<<blocks, 256, 0, stream>>>(h, whi, wlo, bias, out, R);
}